// Round 6
// baseline (444.583 us; speedup 1.0000x reference)
//
#include <hip/hip_runtime.h>
#include <math.h>

#define IN_DIM_C 128
#define OUT_DIM_C 64
#define T_STEPS 8
#define KC_MAX 512          // max coarse buckets (N/256 = 391 actual)
#define PTILE 2048          // edges per k_part block

__device__ __forceinline__ float4 f4zero() { return make_float4(0.f, 0.f, 0.f, 0.f); }

// ---------------- coarse histogram: per-block LDS hist -> global atomics -----------------
__global__ __launch_bounds__(256) void k_hist(const int* __restrict__ dst,
                                              int* __restrict__ chist, int E) {
    __shared__ int hh[KC_MAX];
    const int tid = threadIdx.x;
    for (int i = tid; i < KC_MAX; i += 256) hh[i] = 0;
    __syncthreads();
    long base = (long)blockIdx.x * 4096;
    #pragma unroll
    for (int j = 0; j < 16; ++j) {
        long e = base + j * 256 + tid;
        if (e < E) atomicAdd(&hh[dst[e] >> 8], 1);
    }
    __syncthreads();
    for (int i = tid; i < KC_MAX; i += 256)
        if (hh[i]) atomicAdd(&chist[i], hh[i]);
}

// ---------------- tiny scan: exclusive prefix over kc bucket counts -> gcursor -----------
__global__ __launch_bounds__(64) void k_scanK(const int* __restrict__ chist,
                                              int* __restrict__ gcursor,
                                              int* __restrict__ offsets,
                                              int kc, int n, int E) {
    int lane = threadIdx.x;
    int carry = 0;
    for (int c = 0; c * 64 < kc; ++c) {
        int idx = c * 64 + lane;
        int v = (idx < kc) ? chist[idx] : 0;
        int x = v;
        #pragma unroll
        for (int off = 1; off < 64; off <<= 1) {
            int t = __shfl_up(x, off, 64);
            if (lane >= off) x += t;
        }
        if (idx < kc) gcursor[idx] = carry + x - v;
        carry += __shfl(x, 63, 64);
    }
    if (lane == 0) offsets[n] = E;
}

// ---------------- GEMM: h = x @ W  (fp32 vector ALU) ----------------
__global__ __launch_bounds__(256) void k_gemm(const float* __restrict__ x,
                                              const float* __restrict__ W,
                                              float* __restrict__ h,
                                              int n, int n_groups) {
    __shared__ __align__(16) float Ws[IN_DIM_C * OUT_DIM_C];   // 32 KB, [k][d]
    __shared__ __align__(16) float xs[16 * 136];               // 16 rows, padded stride 136

    for (int i = threadIdx.x; i < IN_DIM_C * OUT_DIM_C / 4; i += 256)
        ((float4*)Ws)[i] = ((const float4*)W)[i];

    const int ln = threadIdx.x >> 4;
    const int dg = threadIdx.x & 15;
    const float4* Ws4 = (const float4*)Ws;

    for (int g = blockIdx.x; g < n_groups; g += gridDim.x) {
        int node_base = g * 16;
        __syncthreads();
        for (int f = threadIdx.x; f < 512; f += 256) {
            int row = f >> 5, c4 = f & 31;
            int node = node_base + row;
            float4 v = f4zero();
            if (node < n) v = *(const float4*)&x[(long)node * IN_DIM_C + c4 * 4];
            *(float4*)&xs[row * 136 + c4 * 4] = v;
        }
        __syncthreads();

        int node = node_base + ln;
        float4 acc = f4zero();
        #pragma unroll
        for (int k = 0; k < IN_DIM_C; k += 4) {
            float4 xv = *(const float4*)&xs[ln * 136 + k];
            float4 w0 = Ws4[(k + 0) * 16 + dg];
            float4 w1 = Ws4[(k + 1) * 16 + dg];
            float4 w2 = Ws4[(k + 2) * 16 + dg];
            float4 w3 = Ws4[(k + 3) * 16 + dg];
            acc.x = fmaf(xv.x, w0.x, acc.x); acc.y = fmaf(xv.x, w0.y, acc.y);
            acc.z = fmaf(xv.x, w0.z, acc.z); acc.w = fmaf(xv.x, w0.w, acc.w);
            acc.x = fmaf(xv.y, w1.x, acc.x); acc.y = fmaf(xv.y, w1.y, acc.y);
            acc.z = fmaf(xv.y, w1.z, acc.z); acc.w = fmaf(xv.y, w1.w, acc.w);
            acc.x = fmaf(xv.z, w2.x, acc.x); acc.y = fmaf(xv.z, w2.y, acc.y);
            acc.z = fmaf(xv.z, w2.z, acc.z); acc.w = fmaf(xv.z, w2.w, acc.w);
            acc.x = fmaf(xv.w, w3.x, acc.x); acc.y = fmaf(xv.w, w3.y, acc.y);
            acc.z = fmaf(xv.w, w3.z, acc.z); acc.w = fmaf(xv.w, w3.w, acc.w);
        }
        if (node < n)
            *(float4*)&h[(long)node * OUT_DIM_C + dg * 4] = acc;
    }
}

// ---------------- coarse partition: direct scattered stores into per-bucket runs ---------
__global__ __launch_bounds__(256) void k_part(const int* __restrict__ src,
                                              const int* __restrict__ dst,
                                              int* __restrict__ gcursor,
                                              int* __restrict__ part, int E, int kc) {
    __shared__ int hist[KC_MAX];
    __shared__ int offs[KC_MAX];
    __shared__ int cur[KC_MAX];
    __shared__ int gbase[KC_MAX];
    const int tid = threadIdx.x;
    long base = (long)blockIdx.x * PTILE;

    for (int i = tid; i < KC_MAX; i += 256) hist[i] = 0;
    __syncthreads();
    #pragma unroll
    for (int j = 0; j < PTILE / 256; ++j) {
        long e = base + j * 256 + tid;
        if (e < E) atomicAdd(&hist[dst[e] >> 8], 1);
    }
    __syncthreads();
    if (tid < 64) {
        int carry = 0;
        for (int c = 0; c * 64 < kc; ++c) {
            int idx = c * 64 + tid;
            int v = (idx < kc) ? hist[idx] : 0;
            int x = v;
            #pragma unroll
            for (int off = 1; off < 64; off <<= 1) {
                int t = __shfl_up(x, off, 64);
                if (tid >= off) x += t;
            }
            if (idx < kc) { offs[idx] = carry + x - v; cur[idx] = carry + x - v; }
            carry += __shfl(x, 63, 64);
        }
    }
    __syncthreads();
    for (int b = tid; b < kc; b += 256)
        gbase[b] = hist[b] ? atomicAdd(&gcursor[b], hist[b]) : 0;
    __syncthreads();
    #pragma unroll
    for (int j = 0; j < PTILE / 256; ++j) {
        long e = base + j * 256 + tid;
        if (e < E) {
            int d = dst[e];
            int b = d >> 8;
            int r = atomicAdd(&cur[b], 1);
            part[gbase[b] + r - offs[b]] = (src[e] << 8) | (d & 255);
        }
    }
}

// ---------------- fine sort within bucket: counting sort in a 16 KB window ---------------
__global__ __launch_bounds__(256) void k_sort(const int* __restrict__ part,
                                              const int* __restrict__ gcursor,
                                              int* __restrict__ part2,
                                              int* __restrict__ offsets,
                                              float* __restrict__ dinv, int n) {
    __shared__ int cnt[256];
    __shared__ int cur[256];
    __shared__ int wsum[4], woff[4];
    const int tid = threadIdx.x;
    const int bkt = blockIdx.x;
    int start = bkt ? gcursor[bkt - 1] : 0;   // post-partition: gcursor[b] == end(b)
    int end = gcursor[bkt];

    cnt[tid] = 0;
    __syncthreads();
    for (int i = start + tid; i < end; i += 256)
        atomicAdd(&cnt[part[i] & 255], 1);
    __syncthreads();

    int v = cnt[tid];
    int lane = tid & 63, wv = tid >> 6;
    int x = v;
    #pragma unroll
    for (int off = 1; off < 64; off <<= 1) {
        int t = __shfl_up(x, off, 64);
        if (lane >= off) x += t;
    }
    if (lane == 63) wsum[wv] = x;
    __syncthreads();
    if (tid == 0) { int c = 0; for (int w = 0; w < 4; ++w) { woff[w] = c; c += wsum[w]; } }
    __syncthreads();
    int myloc = woff[wv] + x - v;            // exclusive local offset
    cur[tid] = myloc;
    int node = (bkt << 8) + tid;
    if (node < n) {
        offsets[node] = start + myloc;
        dinv[node] = rsqrtf((float)(v + 1));
    }
    __syncthreads();

    for (int i = start + tid; i < end; i += 256) {
        int p = part[i];
        int r = atomicAdd(&cur[p & 255], 1);
        part2[start + r] = ((unsigned)p) >> 8;   // src node id
    }
}

// ---------------- fused pull + spiking recurrence: one wave per node, lane = dim ---------
// SAFE ONLY when h/part2/offsets/dinv live outside z_seq (d_ws): spike-phase writes to
// z_seq by one block race with pull-phase reads of other blocks.
__global__ __launch_bounds__(256) void k_pullspike(const int* __restrict__ offsets,
                                                   const int* __restrict__ part2,
                                                   const float* __restrict__ dinv,
                                                   const float* __restrict__ h,
                                                   const float* __restrict__ b,
                                                   float* __restrict__ o_seq,
                                                   float* __restrict__ z_seq, int n) {
    int node = (blockIdx.x * 256 + threadIdx.x) >> 6;
    int lane = threadIdx.x & 63;
    if (node >= n) return;

    int o0 = offsets[node], o1 = offsets[node + 1];
    float dd = dinv[node];
    float g = fmaf(dd * dd, h[(long)node * OUT_DIM_C + lane], b[lane]);
    int i = o0;
    for (; i + 8 <= o1; i += 8) {
        int s[8]; float nr[8], hv[8];
        #pragma unroll
        for (int k = 0; k < 8; ++k) s[k] = part2[i + k];
        #pragma unroll
        for (int k = 0; k < 8; ++k) hv[k] = h[(long)s[k] * OUT_DIM_C + lane];
        #pragma unroll
        for (int k = 0; k < 8; ++k) nr[k] = dinv[s[k]] * dd;
        #pragma unroll
        for (int k = 0; k < 8; ++k) g = fmaf(nr[k], hv[k], g);
    }
    for (; i < o1; ++i) {
        int s = part2[i];
        g = fmaf(dinv[s] * dd, h[(long)s * OUT_DIM_C + lane], g);
    }

    const float s0 = (lane == 0) ? -1.0f : 1.0f;
    const float zo = (lane == 0) ? 1.0f : 0.0f;    // origin

    auto step = [&](float z, float& zn, bool& sp) {
        float p = s0 * z * g;
        p += __shfl_xor(p, 1, 64);  p += __shfl_xor(p, 2, 64);
        p += __shfl_xor(p, 4, 64);  p += __shfl_xor(p, 8, 64);
        p += __shfl_xor(p, 16, 64); p += __shfl_xor(p, 32, 64);
        float u = fmaf(p, z, g);
        float q = s0 * u * u;
        q += __shfl_xor(q, 1, 64);  q += __shfl_xor(q, 2, 64);
        q += __shfl_xor(q, 4, 64);  q += __shfl_xor(q, 8, 64);
        q += __shfl_xor(q, 16, 64); q += __shfl_xor(q, 32, 64);
        float un = sqrtf(fmaxf(q, 1e-7f));
        float c = coshf(un);
        float sh = sinhf(un) / un;
        zn = fmaf(c, z, sh * u);
        float z0 = __shfl(zn, 0, 64);
        float v = acoshf(fmaxf(z0, 1.0f + 1e-7f));
        sp = (v >= 1.0f);
    };

    float z1; bool sp0;
    step(zo, z1, sp0);
    float r0 = sp0 ? zo : z1;

    float z = zo;
    bool at0 = true;
    for (int t = 0; t < T_STEPS; ++t) {
        float zn; bool sp;
        if (at0) { sp = sp0; zn = r0; }
        else {
            step(z, zn, sp);
            if (sp) zn = zo;
        }
        z_seq[(long)t * n * OUT_DIM_C + (long)node * OUT_DIM_C + lane] = zn;
        if (lane == 0) o_seq[(long)t * n + node] = sp ? 1.0f : 0.0f;
        z = zn;
        at0 = sp;
    }
}

// ---------------- unfused fallback pair (scratch aliased into z_seq slabs) ---------------
__global__ __launch_bounds__(256) void k_pull(const int* __restrict__ offsets,
                                              const int* __restrict__ part2,
                                              const float* __restrict__ dinv,
                                              const float* __restrict__ h,
                                              const float* __restrict__ b,
                                              float* __restrict__ agg, int n) {
    int node = (blockIdx.x * 256 + threadIdx.x) >> 6;
    int lane = threadIdx.x & 63;
    if (node >= n) return;
    int o0 = offsets[node], o1 = offsets[node + 1];
    float dd = dinv[node];
    float acc = fmaf(dd * dd, h[(long)node * OUT_DIM_C + lane], b[lane]);
    int i = o0;
    for (; i + 8 <= o1; i += 8) {
        int s[8]; float hv[8];
        #pragma unroll
        for (int k = 0; k < 8; ++k) s[k] = part2[i + k];
        #pragma unroll
        for (int k = 0; k < 8; ++k) hv[k] = h[(long)s[k] * OUT_DIM_C + lane];
        #pragma unroll
        for (int k = 0; k < 8; ++k) acc = fmaf(dinv[s[k]] * dd, hv[k], acc);
    }
    for (; i < o1; ++i) {
        int s = part2[i];
        acc = fmaf(dinv[s] * dd, h[(long)s * OUT_DIM_C + lane], acc);
    }
    agg[(long)node * OUT_DIM_C + lane] = acc;
}

__global__ __launch_bounds__(256) void k_spike(const float* agg,
                                               float* o_seq, float* z_seq, int n) {
    int node = (blockIdx.x * 256 + threadIdx.x) >> 6;
    int lane = threadIdx.x & 63;
    if (node >= n) return;
    float g = agg[(long)node * OUT_DIM_C + lane];
    const float s0 = (lane == 0) ? -1.0f : 1.0f;
    const float zo = (lane == 0) ? 1.0f : 0.0f;

    auto step = [&](float z, float& zn, bool& sp) {
        float p = s0 * z * g;
        p += __shfl_xor(p, 1, 64);  p += __shfl_xor(p, 2, 64);
        p += __shfl_xor(p, 4, 64);  p += __shfl_xor(p, 8, 64);
        p += __shfl_xor(p, 16, 64); p += __shfl_xor(p, 32, 64);
        float u = fmaf(p, z, g);
        float q = s0 * u * u;
        q += __shfl_xor(q, 1, 64);  q += __shfl_xor(q, 2, 64);
        q += __shfl_xor(q, 4, 64);  q += __shfl_xor(q, 8, 64);
        q += __shfl_xor(q, 16, 64); q += __shfl_xor(q, 32, 64);
        float un = sqrtf(fmaxf(q, 1e-7f));
        float c = coshf(un);
        float sh = sinhf(un) / un;
        zn = fmaf(c, z, sh * u);
        float z0 = __shfl(zn, 0, 64);
        float v = acoshf(fmaxf(z0, 1.0f + 1e-7f));
        sp = (v >= 1.0f);
    };

    float z1; bool sp0;
    step(zo, z1, sp0);
    float r0 = sp0 ? zo : z1;

    float z = zo;
    bool at0 = true;
    for (int t = 0; t < T_STEPS; ++t) {
        float zn; bool sp;
        if (at0) { sp = sp0; zn = r0; }
        else {
            step(z, zn, sp);
            if (sp) zn = zo;
        }
        z_seq[(long)t * n * OUT_DIM_C + (long)node * OUT_DIM_C + lane] = zn;
        if (lane == 0) o_seq[(long)t * n + node] = sp ? 1.0f : 0.0f;
        z = zn;
        at0 = sp;
    }
}

extern "C" void kernel_launch(void* const* d_in, const int* in_sizes, int n_in,
                              void* d_out, int out_size, void* d_ws, size_t ws_size,
                              hipStream_t stream) {
    const float* x  = (const float*)d_in[0];
    const int*   ei = (const int*)d_in[1];
    const float* W  = (const float*)d_in[2];
    const float* b  = (const float*)d_in[3];
    const int N = in_sizes[0] / IN_DIM_C;   // 100000
    const int E = in_sizes[1] / 2;          // 1600000
    const int KC = (N + 255) >> 8;          // 391 coarse buckets

    float* out   = (float*)d_out;
    float* o_seq = out;                              // [T, N]
    float* z_seq = out + (long)T_STEPS * N;          // [T, N, 64]

    const int* srcp = ei;
    const int* dstp = ei + E;

    // scratch layout (element counts)
    const long n_h = (long)N * OUT_DIM_C;
    const long n_meta = 2L * KC_MAX + (N + 1) + N;
    const size_t need = (size_t)(n_h + 2L * E + n_meta) * 4;

    float *h; int *part, *part2, *chist, *gcursor, *offsets; float *dinv;
    bool fused = (ws_size >= need);
    if (fused) {
        h       = (float*)d_ws;
        part    = (int*)(h + n_h);
        part2   = part + E;
        chist   = part2 + E;
    } else {
        // fallback: alias into z_seq slabs (round-4 proven layout), unfused epilogue
        h       = z_seq + 1L * n_h;
        part    = (int*)(z_seq + 2L * n_h);
        part2   = (int*)(z_seq + 3L * n_h);
        chist   = (int*)(z_seq + 4L * n_h);
    }
    gcursor = chist + KC_MAX;
    offsets = gcursor + KC_MAX;
    dinv    = (float*)(offsets + N + 1);

    hipMemsetAsync(chist, 0, (size_t)KC_MAX * sizeof(int), stream);
    k_hist<<<(E + 4095) / 4096, 256, 0, stream>>>(dstp, chist, E);
    k_scanK<<<1, 64, 0, stream>>>(chist, gcursor, offsets, KC, N, E);

    int n_groups = (N + 15) / 16;
    k_gemm<<<1024, 256, 0, stream>>>(x, W, h, N, n_groups);

    k_part<<<(E + PTILE - 1) / PTILE, 256, 0, stream>>>(srcp, dstp, gcursor, part, E, KC);
    k_sort<<<KC, 256, 0, stream>>>(part, gcursor, part2, offsets, dinv, N);

    if (fused) {
        k_pullspike<<<(N * 64 + 255) / 256, 256, 0, stream>>>(offsets, part2, dinv, h, b,
                                                              o_seq, z_seq, N);
    } else {
        float* agg = z_seq;   // slab 0
        k_pull<<<(N * 64 + 255) / 256, 256, 0, stream>>>(offsets, part2, dinv, h, b, agg, N);
        k_spike<<<(N * 64 + 255) / 256, 256, 0, stream>>>(agg, o_seq, z_seq, N);
    }
}